// Round 2
// baseline (160.055 us; speedup 1.0000x reference)
//
#include <hip/hip_runtime.h>
#include <stdint.h>

typedef __attribute__((ext_vector_type(8))) short  bf16x8;
typedef __attribute__((ext_vector_type(4))) short  short4v;
typedef __attribute__((ext_vector_type(4))) float  f32x4;
typedef __attribute__((ext_vector_type(4))) float  float4v;

__device__ __forceinline__ unsigned short f2bf(float f) {
  unsigned int u = __builtin_bit_cast(unsigned int, f);
  u += 0x7FFFu + ((u >> 16) & 1u);          // round-to-nearest-even
  return (unsigned short)(u >> 16);
}

__device__ __forceinline__ void async_ld16(const void* g, void* l) {
  __builtin_amdgcn_global_load_lds(
      (const __attribute__((address_space(1))) void*)g,
      (__attribute__((address_space(3))) void*)l,
      16, 0, 0);
}

// ---------------------------------------------------------------- casts ----
__global__ __launch_bounds__(256) void cast4_bf16(
    const float* __restrict__ in, unsigned short* __restrict__ out, int n4) {
  int i = blockIdx.x * 256 + threadIdx.x;
  if (i >= n4) return;
  float4v v = *(const float4v*)(in + (size_t)i * 4);
  short4v o;
  o[0] = (short)f2bf(v[0]); o[1] = (short)f2bf(v[1]);
  o[2] = (short)f2bf(v[2]); o[3] = (short)f2bf(v[3]);
  *(short4v*)(out + (size_t)i * 4) = o;
}

// in: R x C fp32 (row-major)  ->  out: C x R bf16 (row-major) == in^T
__global__ __launch_bounds__(256) void transpose_cast(
    const float* __restrict__ in, unsigned short* __restrict__ out,
    int R, int C) {
  __shared__ float tile[32][33];
  const int tx = threadIdx.x & 31, ty = threadIdx.x >> 5;   // 32 x 8
  const int c0 = blockIdx.x * 32, r0 = blockIdx.y * 32;
  #pragma unroll
  for (int rr = ty; rr < 32; rr += 8)
    tile[rr][tx] = in[(size_t)(r0 + rr) * C + c0 + tx];
  __syncthreads();
  #pragma unroll
  for (int cc = ty; cc < 32; cc += 8)
    out[(size_t)(c0 + cc) * R + r0 + tx] = f2bf(tile[tx][cc]);
}

// ------------------------------------------------------- pipelined GEMM ----
// C[M,N] = A[M,K] * BT[N,K]^T
// 512 thr (8 waves, 2Mx4N), tile 128x256, BK=64, dbuf LDS w/ XOR swizzle,
// counted vmcnt(6) (T4), setprio (T5), XCD swizzle (T1).
template<int BF16_OUT>
__global__ __launch_bounds__(512, 1) void gemm_pipe(
    const unsigned short* __restrict__ A,
    const unsigned short* __restrict__ BT,
    void* __restrict__ Cout,
    const float* __restrict__ bias,
    int M, int N, int K) {
  constexpr int BM = 128, BN = 256, BK = 64;
  __shared__ __align__(16) unsigned short lsA[2 * BM * BK];   // 32 KB
  __shared__ __align__(16) unsigned short lsB[2 * BN * BK];   // 64 KB
  const int tid = threadIdx.x;
  const int w = tid >> 6, ln = tid & 63;

  // XCD-aware block swizzle (bijective: grid % 8 == 0 for both call sites)
  const int nwgx = gridDim.x;
  int wid = blockIdx.y * nwgx + blockIdx.x;
  const int nwg = nwgx * gridDim.y;
  if ((nwg & 7) == 0) { const int q = nwg >> 3; wid = (wid & 7) * q + (wid >> 3); }
  const int bm = (wid / nwgx) * BM, bn = (wid % nwgx) * BN;

  const int wm = w >> 2, wn = w & 3;         // wave tile: 64 rows x 64 cols
  const int NT = K / BK;

  // ---- staging addresses (per-lane global src is XOR-pre-swizzled) ----
  const int r8 = ln >> 3, s8 = ln & 7;
  const int csw = (s8 ^ r8) * 8;             // swizzled col (elements)
  const unsigned short* gAb = A  + (size_t)(bm + w * 16 + r8) * K + csw;
  const unsigned short* gBb = BT + (size_t)(bn + w * 32 + r8) * K + csw;

#define STAGE(buf, t) do {                                                  \
    const unsigned short* ga = gAb + (size_t)(t) * BK;                      \
    const unsigned short* gb = gBb + (size_t)(t) * BK;                      \
    unsigned short* la = &lsA[(buf) * BM * BK + (w * 16) * BK];             \
    unsigned short* lb = &lsB[(buf) * BN * BK + (w * 32) * BK];             \
    async_ld16(ga,                 la);                                     \
    async_ld16(ga + (size_t)8 * K, la + 8 * BK);                            \
    async_ld16(gb,                 lb);                                     \
    async_ld16(gb + (size_t)8 * K, lb + 8 * BK);                            \
    async_ld16(gb + (size_t)16 * K, lb + 16 * BK);                          \
    async_ld16(gb + (size_t)24 * K, lb + 24 * BK);                          \
  } while (0)

  // ---- fragment read offsets (swizzled byte addr, 2-way-max banks) ----
  const int lr = ln & 15, lq = ln >> 4, l7 = ln & 7;

  f32x4 acc[4][4] = {};

  // prologue: tiles 0,1 in flight (12 loads); wait tile 0 (6 left)
  STAGE(0, 0);
  STAGE(1, 1);
  asm volatile("s_waitcnt vmcnt(6)" ::: "memory");
  __builtin_amdgcn_sched_barrier(0);
  __builtin_amdgcn_s_barrier();
  __builtin_amdgcn_sched_barrier(0);

  for (int t = 0; t < NT; ++t) {
    const int cur = t & 1;
    const char* pA = (const char*)lsA + cur * (BM * BK * 2);
    const char* pB = (const char*)lsB + cur * (BN * BK * 2);
    #pragma unroll
    for (int ks = 0; ks < 2; ++ks) {
      const int kb = (ks * 64 + lq * 16) ^ (l7 << 4);
      bf16x8 af[4], bfr[4];
      #pragma unroll
      for (int i = 0; i < 4; ++i) {
        af[i]  = *(const bf16x8*)(pA + (wm * 64 + i * 16 + lr) * 128 + kb);
        bfr[i] = *(const bf16x8*)(pB + (wn * 64 + i * 16 + lr) * 128 + kb);
      }
      __builtin_amdgcn_s_setprio(1);
      #pragma unroll
      for (int m = 0; m < 4; ++m)
        #pragma unroll
        for (int n = 0; n < 4; ++n)
          acc[m][n] = __builtin_amdgcn_mfma_f32_16x16x32_bf16(af[m], bfr[n], acc[m][n], 0, 0, 0);
      __builtin_amdgcn_s_setprio(0);
      __builtin_amdgcn_sched_barrier(0);
      __builtin_amdgcn_s_barrier();          // ks=0: phase sync; ks=1: end-of-reads
      __builtin_amdgcn_sched_barrier(0);
    }
    // buf[cur] fully read by all waves -> safe to restage it
    if (t + 2 < NT) {
      STAGE(cur, t + 2);                      // outstanding: 6 (t+1) + 6 (t+2)
      asm volatile("s_waitcnt vmcnt(6)" ::: "memory");   // tile t+1 landed
    } else if (t + 1 < NT) {
      asm volatile("s_waitcnt vmcnt(0)" ::: "memory");   // last tile: drain
    }
    __builtin_amdgcn_sched_barrier(0);
    __builtin_amdgcn_s_barrier();
    __builtin_amdgcn_sched_barrier(0);
  }
#undef STAGE

  // ---- epilogue ----
  if (BF16_OUT) {
    unsigned short* C = (unsigned short*)Cout;
    #pragma unroll
    for (int m = 0; m < 4; ++m)
      #pragma unroll
      for (int i = 0; i < 4; ++i) {
        size_t r = (size_t)(bm + wm * 64 + m * 16 + lq * 4 + i);
        #pragma unroll
        for (int n = 0; n < 4; ++n)
          C[r * N + bn + wn * 64 + n * 16 + lr] = f2bf(acc[m][n][i]);
      }
  } else {
    float* C = (float*)Cout;
    float bv[4];
    #pragma unroll
    for (int n = 0; n < 4; ++n)
      bv[n] = bias ? bias[bn + wn * 64 + n * 16 + lr] : 0.f;
    #pragma unroll
    for (int m = 0; m < 4; ++m)
      #pragma unroll
      for (int i = 0; i < 4; ++i) {
        size_t r = (size_t)(bm + wm * 64 + m * 16 + lq * 4 + i);
        #pragma unroll
        for (int n = 0; n < 4; ++n)
          C[r * N + bn + wn * 64 + n * 16 + lr] = acc[m][n][i] + bv[n];
      }
  }
}

// ------------------------------------------------- M^T = scale*(k^T v)^T ---
__global__ __launch_bounds__(256) void kv_outer(
    const unsigned short* __restrict__ qkv,
    unsigned short* __restrict__ MT, float scale) {
  const int bid = blockIdx.x;                 // b*32 + h*2 + half
  const int b = bid >> 5, h = (bid >> 1) & 15, hf = bid & 1;
  const size_t base = ((size_t)(b * 2048 + hf * 1024)) * 3072 + h * 64;
  const unsigned short* kp = qkv + base + 1024;
  const unsigned short* vp = qkv + base + 2048;
  __shared__ __align__(16) unsigned short kT[64][136];
  __shared__ __align__(16) unsigned short vT[64][136];
  const int tid = threadIdx.x, wv = tid >> 6, ln = tid & 63;
  f32x4 acc[4] = {};
  const int e4 = (tid & 15) * 4;
  const int jr = tid >> 4;
  const int fr = ln & 15, ko = (ln >> 4) * 8;

  for (int j0 = 0; j0 < 1024; j0 += 128) {
    __syncthreads();
    #pragma unroll
    for (int jj = 0; jj < 128; jj += 16) {
      int j = jj + jr;
      size_t go = (size_t)(j0 + j) * 3072 + e4;
      short4v k4 = *(const short4v*)(kp + go);
      short4v v4 = *(const short4v*)(vp + go);
      #pragma unroll
      for (int t = 0; t < 4; t++) {
        kT[e4 + t][j] = (unsigned short)k4[t];
        vT[e4 + t][j] = (unsigned short)v4[t];
      }
    }
    __syncthreads();
    #pragma unroll
    for (int kk = 0; kk < 128; kk += 32) {
      bf16x8 af = *(const bf16x8*)&kT[wv * 16 + fr][kk + ko];
      #pragma unroll
      for (int n = 0; n < 4; n++) {
        bf16x8 bf2 = *(const bf16x8*)&vT[n * 16 + fr][kk + ko];
        acc[n] = __builtin_amdgcn_mfma_f32_16x16x32_bf16(af, bf2, acc[n], 0, 0, 0);
      }
    }
  }
  unsigned short* outp = MT + (size_t)bid * 4096;       // [d][e], 64x64
  #pragma unroll
  for (int n = 0; n < 4; n++)
    #pragma unroll
    for (int i = 0; i < 4; i++) {
      int d = n * 16 + fr;
      int e = wv * 16 + (ln >> 4) * 4 + i;
      outp[d * 64 + e] = f2bf(acc[n][i] * scale);
    }
}

// ------------------------------------------------------------ o = q * M ----
__global__ __launch_bounds__(256) void apply_q(
    const unsigned short* __restrict__ qkv,
    const unsigned short* __restrict__ MT,
    unsigned short* __restrict__ o) {
  const int bid = blockIdx.x;     // ((b*16+h)*2 + lhalf)*16 + lt
  const int lt = bid & 15, hf = (bid >> 4) & 1, h = (bid >> 5) & 15, b = bid >> 9;
  const int l0 = hf * 1024 + lt * 64;
  const unsigned short* qp = qkv + ((size_t)(b * 2048 + l0)) * 3072 + h * 64;
  const unsigned short* mp = MT + ((size_t)((b * 16 + h) * 2 + (1 - hf))) * 4096;
  const int tid = threadIdx.x, wv = tid >> 6, ln = tid & 63;
  const int fr = ln & 15, ko = (ln >> 4) * 8;
  f32x4 acc[4] = {};
  #pragma unroll
  for (int kk = 0; kk < 2; kk++) {
    bf16x8 af = *(const bf16x8*)(qp + (size_t)(wv * 16 + fr) * 3072 + kk * 32 + ko);
    #pragma unroll
    for (int n = 0; n < 4; n++) {
      bf16x8 bf2 = *(const bf16x8*)(mp + (n * 16 + fr) * 64 + kk * 32 + ko);
      acc[n] = __builtin_amdgcn_mfma_f32_16x16x32_bf16(af, bf2, acc[n], 0, 0, 0);
    }
  }
  unsigned short* op = o + ((size_t)(b * 2048 + l0)) * 1024 + h * 64;
  #pragma unroll
  for (int n = 0; n < 4; n++)
    #pragma unroll
    for (int i = 0; i < 4; i++)
      op[(size_t)(wv * 16 + (ln >> 4) * 4 + i) * 1024 + n * 16 + fr] = f2bf(acc[n][i]);
}

// ---------------------------------------------------------------------------
extern "C" void kernel_launch(void* const* d_in, const int* in_sizes, int n_in,
                              void* d_out, int out_size, void* d_ws, size_t ws_size,
                              hipStream_t stream) {
  const float* x     = (const float*)d_in[0];   // 4 x 2048 x 1024
  const float* Wqkv  = (const float*)d_in[1];   // 1024 x 3072
  const float* Wproj = (const float*)d_in[2];   // 1024 x 1024
  const float* bproj = (const float*)d_in[3];   // 1024
  float* out = (float*)d_out;                   // 8192 x 1024

  char* ws = (char*)d_ws;
  unsigned short* xb     = (unsigned short*)(ws);               // 16.78 MB
  unsigned short* wqkvT  = (unsigned short*)(ws + 16777216);    //  6.29 MB
  unsigned short* wprojT = (unsigned short*)(ws + 23068672);    //  2.10 MB
  unsigned short* qkv    = (unsigned short*)(ws + 25165824);    // 50.33 MB
  unsigned short* MT     = (unsigned short*)(ws + 75497472);    //  1.05 MB
  unsigned short* ob     = (unsigned short*)(ws + 76546048);    // 16.78 MB

  // casts / transposes
  cast4_bf16<<<8192, 256, 0, stream>>>(x, xb, 2097152);
  transpose_cast<<<dim3(96, 32), 256, 0, stream>>>(Wqkv, wqkvT, 1024, 3072);
  transpose_cast<<<dim3(32, 32), 256, 0, stream>>>(Wproj, wprojT, 1024, 1024);

  // qkv = x @ W_qkv   (8192 x 3072, bf16 out) — 768 blocks (%8==0)
  gemm_pipe<1><<<dim3(12, 64), 512, 0, stream>>>(xb, wqkvT, (void*)qkv, nullptr,
                                                 8192, 3072, 1024);
  // M^T = scale * (k^T v)^T per (b,h,half)
  kv_outer<<<128, 256, 0, stream>>>(qkv, MT, 0.125f);
  // o = q @ M(other half)
  apply_q<<<2048, 256, 0, stream>>>(qkv, MT, ob);
  // out = o @ W_proj + b  (fp32 out) — 256 blocks (%8==0)
  gemm_pipe<0><<<dim3(4, 64), 512, 0, stream>>>(ob, wprojT, (void*)out, bproj,
                                                8192, 1024, 1024);
}